// Round 2
// baseline (488.278 us; speedup 1.0000x reference)
//
#include <hip/hip_runtime.h>
#include <hip/hip_bf16.h>
#include <math.h>

typedef __hip_bfloat16 BF;
typedef __bf16 bf16x8 __attribute__((ext_vector_type(8)));
typedef float f32x4 __attribute__((ext_vector_type(4)));

struct alignas(8) BF4 { BF v[4]; };

static __device__ __forceinline__ float b2f(BF x) { return __bfloat162float(x); }
static __device__ __forceinline__ BF f2b(float x) { return __float2bfloat16(x); }

// async global->LDS, 16B per lane; LDS dest must be wave-uniform base (+lane*16 implicit)
static __device__ __forceinline__ void gld_lds16(const void* g, void* l) {
  __builtin_amdgcn_global_load_lds(
      (const __attribute__((address_space(1))) unsigned int*)g,
      (__attribute__((address_space(3))) unsigned int*)l, 16, 0, 0);
}

// ---------------------------------------------------------------------------
// f32 -> bf16 convert, 4 elements/thread, grid-stride
// ---------------------------------------------------------------------------
__global__ void __launch_bounds__(256) cvt_kernel(
    const float* __restrict__ in, BF* __restrict__ out, int n4) {
  for (int i = blockIdx.x * 256 + threadIdx.x; i < n4; i += gridDim.x * 256) {
    float4 v = ((const float4*)in)[i];
    BF4 o;
    o.v[0] = f2b(v.x); o.v[1] = f2b(v.y); o.v[2] = f2b(v.z); o.v[3] = f2b(v.w);
    ((BF4*)out)[i] = o;
  }
}

// ---------------------------------------------------------------------------
// rel-bias kernel: one thread per (window w, l=i*4+j). out[w*128 + p*16 + l], fp32.
// sp[c][i] = s_pos[b, (c*4+i)&1, wi, (c*4+i)>>1]; xp[c][j] = x_pos[b, j*4096+wi, c]
// ---------------------------------------------------------------------------
__global__ void __launch_bounds__(256) bias_kernel(
    const float* __restrict__ s_pos, const float* __restrict__ x_pos,
    const float* __restrict__ pw1, const float* __restrict__ pb1,
    const float* __restrict__ bn_g, const float* __restrict__ bn_b,
    const float* __restrict__ bn_m, const float* __restrict__ bn_v,
    const float* __restrict__ pw2, const float* __restrict__ pb2,
    float* __restrict__ out) {
  int gid = blockIdx.x * 256 + threadIdx.x;   // [0, 16384*16)
  int w = gid >> 4, l = gid & 15;
  int b = w >> 12, wi = w & 4095;
  int i = l >> 2, j = l & 3;
  int e0 = i, e1 = 4 + i;
  float sp0 = s_pos[(((size_t)b * 2 + (e0 & 1)) * 4096 + wi) * 4 + (e0 >> 1)];
  float sp1 = s_pos[(((size_t)b * 2 + (e1 & 1)) * 4096 + wi) * 4 + (e1 >> 1)];
  float xp0 = x_pos[((size_t)b * 16384 + j * 4096 + wi) * 2 + 0];
  float xp1 = x_pos[((size_t)b * 16384 + j * 4096 + wi) * 2 + 1];
  float r0 = sp0 - xp0, r1 = sp1 - xp1;
  float acc[8];
#pragma unroll
  for (int p = 0; p < 8; ++p) acc[p] = pb2[p];
#pragma unroll
  for (int o = 0; o < 16; ++o) {
    float t = pw1[o * 2 + 0] * r0 + pw1[o * 2 + 1] * r1 + pb1[o];
    float sc = bn_g[o] / sqrtf(bn_v[o] + 1e-5f);
    t = (t - bn_m[o]) * sc + bn_b[o];
    t = fmaxf(t, 0.0f);
#pragma unroll
    for (int p = 0; p < 8; ++p) acc[p] += pw2[p * 16 + o] * t;
  }
#pragma unroll
  for (int p = 0; p < 8; ++p) out[(size_t)w * 128 + p * 16 + l] = acc[p];
}

// ---------------------------------------------------------------------------
// Generic TN bf16 MFMA GEMM: C[m,n] = epi(sum_k A[m,k]*Bw[n,k] + bias[n])
// A: (M,K) row-major, Bw: (N,K) row-major, both bf16; bias f32; C type CT.
// 128x128 tile, BK=64, 4 waves 2x2, 16x16x32 MFMA, global_load_lds staging
// into chunked LDS [BK/8][128][8].
// ---------------------------------------------------------------------------
enum { EPI_NONE = 0, EPI_RES = 1, EPI_GELU = 2 };

template <int EPI, typename CT>
__global__ void __launch_bounds__(256, 2) gemm_tn(
    const BF* __restrict__ A, const BF* __restrict__ Bw,
    const float* __restrict__ bias, const BF* __restrict__ Res,
    CT* __restrict__ C, int M, int N, int K) {
  alignas(16) __shared__ BF As[8][128][8];
  alignas(16) __shared__ BF Bs[8][128][8];
  const int ntiles = N >> 7;
  const int mt = blockIdx.x / ntiles;
  const int nt = blockIdx.x % ntiles;
  const int row0 = mt << 7, col0 = nt << 7;
  const int t = threadIdx.x;
  const int wave = t >> 6, lane = t & 63;
  const int wr = wave >> 1, wc = wave & 1;
  f32x4 acc[4][4] = {};

  for (int k0 = 0; k0 < K; k0 += 64) {
    __syncthreads();  // previous compute done before LDS overwrite
#pragma unroll
    for (int i = 0; i < 4; ++i) {
      const int e = i * 256 + t;
      const int kc = e >> 7, m = e & 127;
      gld_lds16(A + (size_t)(row0 + m) * K + (k0 + kc * 8),
                &As[0][0][0] + (i * 256 + wave * 64) * 8);
      gld_lds16(Bw + (size_t)(col0 + m) * K + (k0 + kc * 8),
                &Bs[0][0][0] + (i * 256 + wave * 64) * 8);
    }
    __syncthreads();  // compiler emits vmcnt(0) before barrier: staged data visible
#pragma unroll
    for (int kk = 0; kk < 2; ++kk) {
      const int chunk = kk * 4 + (lane >> 4);
      const int rl = lane & 15;
      bf16x8 af[4], bfr[4];
#pragma unroll
      for (int mi = 0; mi < 4; ++mi)
        af[mi] = *(const bf16x8*)(&As[chunk][wr * 64 + mi * 16 + rl][0]);
#pragma unroll
      for (int ni = 0; ni < 4; ++ni)
        bfr[ni] = *(const bf16x8*)(&Bs[chunk][wc * 64 + ni * 16 + rl][0]);
#pragma unroll
      for (int mi = 0; mi < 4; ++mi)
#pragma unroll
        for (int ni = 0; ni < 4; ++ni)
          acc[mi][ni] = __builtin_amdgcn_mfma_f32_16x16x32_bf16(
              af[mi], bfr[ni], acc[mi][ni], 0, 0, 0);
    }
  }
  // epilogue: D layout col = lane&15, row = (lane>>4)*4 + r (m89-verified)
  const int rl = lane & 15, rg = lane >> 4;
#pragma unroll
  for (int mi = 0; mi < 4; ++mi) {
#pragma unroll
    for (int ni = 0; ni < 4; ++ni) {
      const int col = col0 + wc * 64 + ni * 16 + rl;
      const float bcol = bias[col];
#pragma unroll
      for (int r = 0; r < 4; ++r) {
        const int row = row0 + wr * 64 + mi * 16 + rg * 4 + r;
        float v = acc[mi][ni][r] + bcol;
        if constexpr (EPI == EPI_GELU)
          v = 0.5f * v * (1.0f + erff(v * 0.70710678118654752f));
        if constexpr (EPI == EPI_RES)
          v += b2f(Res[(size_t)row * N + col]);
        if constexpr (__is_same(CT, float))
          C[(size_t)row * N + col] = v;
        else
          C[(size_t)row * N + col] = f2b(v);
      }
    }
  }
}

// ---------------------------------------------------------------------------
// Windowed attention: block = 1 window, 32-lane group per head (lane = hd).
// Q gather uses the faithful-.view scramble:
//   q[w,nh,qi,hd] = Qproj[b, nh*2048 + hd*64 + qi*16 + (wi>>8), wi&255]
// K/V: k[w,nh,kj,hd] = Kproj[b, kj*4096 + wi, nh*32+hd]
// Output: O[b, qi*4096 + wi, nh*32+hd]  (bf16, staged in d_out)
// ---------------------------------------------------------------------------
__global__ void __launch_bounds__(256) attn_kernel(
    const BF* __restrict__ Q, const BF* __restrict__ Kp,
    const BF* __restrict__ Vp, const float* __restrict__ bias,
    BF* __restrict__ O) {
  const int w = blockIdx.x;
  const int b = w >> 12, wi = w & 4095;
  const int t = threadIdx.x;
  const int nh = t >> 5, hd = t & 31;
  const float SCALE = 0.17677669529663689f;  // 32^-0.5
  float q[4], kv[4], vv[4];
  const int cq = wi & 255;
  const int lqb = nh * 2048 + hd * 64 + (wi >> 8);
#pragma unroll
  for (int qi = 0; qi < 4; ++qi)
    q[qi] = b2f(Q[((size_t)b * 16384 + lqb + qi * 16) * 256 + cq]) * SCALE;
#pragma unroll
  for (int kj = 0; kj < 4; ++kj) {
    const size_t off = ((size_t)b * 16384 + kj * 4096 + wi) * 256 + nh * 32 + hd;
    kv[kj] = b2f(Kp[off]);
    vv[kj] = b2f(Vp[off]);
  }
  float sc[4][4];
#pragma unroll
  for (int qi = 0; qi < 4; ++qi)
#pragma unroll
    for (int kj = 0; kj < 4; ++kj) {
      float p = q[qi] * kv[kj];
      p += __shfl_xor(p, 1);
      p += __shfl_xor(p, 2);
      p += __shfl_xor(p, 4);
      p += __shfl_xor(p, 8);
      p += __shfl_xor(p, 16);
      sc[qi][kj] = p + bias[(size_t)w * 128 + nh * 16 + qi * 4 + kj];
    }
#pragma unroll
  for (int qi = 0; qi < 4; ++qi) {
    float mx = fmaxf(fmaxf(sc[qi][0], sc[qi][1]), fmaxf(sc[qi][2], sc[qi][3]));
    float e0 = __expf(sc[qi][0] - mx), e1 = __expf(sc[qi][1] - mx);
    float e2 = __expf(sc[qi][2] - mx), e3 = __expf(sc[qi][3] - mx);
    float inv = 1.0f / (e0 + e1 + e2 + e3);
    float o = (e0 * vv[0] + e1 * vv[1] + e2 * vv[2] + e3 * vv[3]) * inv;
    O[((size_t)b * 16384 + qi * 4096 + wi) * 256 + nh * 32 + hd] = f2b(o);
  }
}

// ---------------------------------------------------------------------------
// LayerNorm over C=256: one 64-lane wave per row, 4 bf16 per lane.
// ---------------------------------------------------------------------------
__global__ void __launch_bounds__(256) ln_kernel(
    const BF* __restrict__ S1, const float* __restrict__ g,
    const float* __restrict__ be, BF* __restrict__ Nout) {
  const int wave = threadIdx.x >> 6, lane = threadIdx.x & 63;
  const size_t row = (size_t)blockIdx.x * 4 + wave;
  BF4 d = *(const BF4*)(S1 + row * 256 + lane * 4);
  float x[4] = {b2f(d.v[0]), b2f(d.v[1]), b2f(d.v[2]), b2f(d.v[3])};
  float s = x[0] + x[1] + x[2] + x[3];
  float sq = x[0] * x[0] + x[1] * x[1] + x[2] * x[2] + x[3] * x[3];
#pragma unroll
  for (int m = 1; m <= 32; m <<= 1) {
    s += __shfl_xor(s, m);
    sq += __shfl_xor(sq, m);
  }
  const float mean = s * 0.00390625f;
  const float var = sq * 0.00390625f - mean * mean;
  const float rstd = 1.0f / sqrtf(var + 1e-5f);
  BF4 o;
#pragma unroll
  for (int jj = 0; jj < 4; ++jj) {
    float nv = (x[jj] - mean) * rstd * g[lane * 4 + jj] + be[lane * 4 + jj];
    o.v[jj] = f2b(nv);
  }
  *(BF4*)(Nout + row * 256 + lane * 4) = o;
}

// ---------------------------------------------------------------------------
// ws layout (bytes):
//   [0,          8388608)   bias fp32 (nW*128)
//   [8388608,    41943040)  s_bf  -> aliased as S1 (safe: epi reads Res[i] before C[i] write)
//   [41943040,   75497472)  x_bf
//   [75497472,   109051904) Qproj -> reused as LN output after attn
//   [109051904,  142606336) Kproj -> reused as MLP hidden (H2 spans K+V, 64MB) after attn
//   [142606336,  176160768) Vproj
//   [176160768,  177733632) bf16 weights: Wq,Wk,Wv,Wo (128KB each), mw1,mw2 (512KB each)
// d_out (f32, 64MB) doubles as bf16 attention-output staging (first 32MB),
// consumed by the Wo-GEMM before MLP2 overwrites d_out with the final f32.
// ---------------------------------------------------------------------------
extern "C" void kernel_launch(void* const* d_in, const int* in_sizes, int n_in,
                              void* d_out, int out_size, void* d_ws, size_t ws_size,
                              hipStream_t stream) {
  const float* s     = (const float*)d_in[0];
  const float* x     = (const float*)d_in[1];
  const float* s_pos = (const float*)d_in[2];
  const float* x_pos = (const float*)d_in[3];
  const float* Wq = (const float*)d_in[4];  const float* bq = (const float*)d_in[5];
  const float* Wk = (const float*)d_in[6];  const float* bk = (const float*)d_in[7];
  const float* Wv = (const float*)d_in[8];  const float* bv = (const float*)d_in[9];
  const float* Wo = (const float*)d_in[10]; const float* bo = (const float*)d_in[11];
  const float* pw1 = (const float*)d_in[12]; const float* pb1 = (const float*)d_in[13];
  const float* bn_g = (const float*)d_in[14]; const float* bn_b = (const float*)d_in[15];
  const float* bn_m = (const float*)d_in[16]; const float* bn_v = (const float*)d_in[17];
  const float* pw2 = (const float*)d_in[18]; const float* pb2 = (const float*)d_in[19];
  const float* ln_g = (const float*)d_in[20]; const float* ln_b = (const float*)d_in[21];
  const float* mw1 = (const float*)d_in[22]; const float* mb1 = (const float*)d_in[23];
  const float* mw2 = (const float*)d_in[24]; const float* mb2 = (const float*)d_in[25];

  char* ws = (char*)d_ws;
  float* biasb = (float*)ws;
  BF* s_bf = (BF*)(ws + 8388608);
  BF* x_bf = (BF*)(ws + 41943040);
  BF* Qw   = (BF*)(ws + 75497472);
  BF* Kw   = (BF*)(ws + 109051904);
  BF* Vw   = (BF*)(ws + 142606336);
  BF* Wq_bf  = (BF*)(ws + 176160768);
  BF* Wk_bf  = (BF*)(ws + 176291840);
  BF* Wv_bf  = (BF*)(ws + 176422912);
  BF* Wo_bf  = (BF*)(ws + 176553984);
  BF* mw1_bf = (BF*)(ws + 176685056);
  BF* mw2_bf = (BF*)(ws + 177209344);
  BF* S1 = s_bf;   // alias: Wo-GEMM epilogue reads Res before writing C, per-element
  BF* Nw = Qw;     // LN output reuses Q region (free after attn)
  BF* H2 = Kw;     // MLP hidden reuses K+V regions (free after attn)
  BF* ObBF = (BF*)d_out;  // attn output staged bf16 inside d_out
  float* Of = (float*)d_out;

  cvt_kernel<<<4096, 256, 0, stream>>>(s, s_bf, 4194304);
  cvt_kernel<<<4096, 256, 0, stream>>>(x, x_bf, 4194304);
  cvt_kernel<<<64, 256, 0, stream>>>(Wq, Wq_bf, 16384);
  cvt_kernel<<<64, 256, 0, stream>>>(Wk, Wk_bf, 16384);
  cvt_kernel<<<64, 256, 0, stream>>>(Wv, Wv_bf, 16384);
  cvt_kernel<<<64, 256, 0, stream>>>(Wo, Wo_bf, 16384);
  cvt_kernel<<<256, 256, 0, stream>>>(mw1, mw1_bf, 65536);
  cvt_kernel<<<256, 256, 0, stream>>>(mw2, mw2_bf, 65536);

  bias_kernel<<<1024, 256, 0, stream>>>(s_pos, x_pos, pw1, pb1, bn_g, bn_b,
                                        bn_m, bn_v, pw2, pb2, biasb);
  gemm_tn<EPI_NONE, BF><<<1024, 256, 0, stream>>>(s_bf, Wq_bf, bq, nullptr, Qw, 65536, 256, 256);
  gemm_tn<EPI_NONE, BF><<<1024, 256, 0, stream>>>(x_bf, Wk_bf, bk, nullptr, Kw, 65536, 256, 256);
  gemm_tn<EPI_NONE, BF><<<1024, 256, 0, stream>>>(x_bf, Wv_bf, bv, nullptr, Vw, 65536, 256, 256);
  attn_kernel<<<16384, 256, 0, stream>>>(Qw, Kw, Vw, biasb, ObBF);
  gemm_tn<EPI_RES, BF><<<1024, 256, 0, stream>>>(ObBF, Wo_bf, bo, s_bf, S1, 65536, 256, 256);
  ln_kernel<<<16384, 256, 0, stream>>>(S1, ln_g, ln_b, Nw);
  for (int h = 0; h < 2; ++h) {
    const size_t ro = (size_t)h * 32768;
    gemm_tn<EPI_GELU, BF><<<2048, 256, 0, stream>>>(Nw + ro * 256, mw1_bf, mb1, nullptr,
                                                    H2, 32768, 1024, 256);
    gemm_tn<EPI_RES, float><<<512, 256, 0, stream>>>(H2, mw2_bf, mb2, S1 + ro * 256,
                                                     Of + ro * 256, 32768, 256, 1024);
  }
}

// Round 3
// 458.185 us; speedup vs baseline: 1.0657x; 1.0657x over previous
//
#include <hip/hip_runtime.h>
#include <hip/hip_bf16.h>
#include <math.h>

typedef __hip_bfloat16 BF;
typedef __bf16 bf16x8 __attribute__((ext_vector_type(8)));
typedef float f32x4 __attribute__((ext_vector_type(4)));

struct alignas(8) BF4 { BF v[4]; };

static __device__ __forceinline__ float b2f(BF x) { return __bfloat162float(x); }
static __device__ __forceinline__ BF f2b(float x) { return __float2bfloat16(x); }

// async global->LDS, 16B per lane; LDS dest = wave-uniform base (+lane*16 implicit)
static __device__ __forceinline__ void gld_lds16(const void* g, void* l) {
  __builtin_amdgcn_global_load_lds(
      (const __attribute__((address_space(1))) unsigned int*)g,
      (__attribute__((address_space(3))) unsigned int*)l, 16, 0, 0);
}

// ---------------------------------------------------------------------------
// f32 -> bf16 convert, 4 elements/thread, grid-stride
// ---------------------------------------------------------------------------
__global__ void __launch_bounds__(256) cvt_kernel(
    const float* __restrict__ in, BF* __restrict__ out, int n4) {
  for (int i = blockIdx.x * 256 + threadIdx.x; i < n4; i += gridDim.x * 256) {
    float4 v = ((const float4*)in)[i];
    BF4 o;
    o.v[0] = f2b(v.x); o.v[1] = f2b(v.y); o.v[2] = f2b(v.z); o.v[3] = f2b(v.w);
    ((BF4*)out)[i] = o;
  }
}

// ---------------------------------------------------------------------------
// Build interleaved KV weight: Wkv[2*n+0] = Wk[n], Wkv[2*n+1] = Wv[n] (bf16),
// and interleaved bias bkv[2*n+{0,1}] = {bk,bv}[n] (f32). 64 blocks x 256.
// ---------------------------------------------------------------------------
__global__ void __launch_bounds__(256) cvt_kv_kernel(
    const float* __restrict__ Wk, const float* __restrict__ Wv,
    const float* __restrict__ bk, const float* __restrict__ bv,
    BF* __restrict__ Wkv, float* __restrict__ bkv) {
  int u = blockIdx.x * 256 + threadIdx.x;  // [0, 16384)
  int r = u >> 5, c8 = u & 31;
  const float* src = ((r & 1) ? Wv : Wk) + (size_t)(r >> 1) * 256 + c8 * 8;
  float4 a = ((const float4*)src)[0];
  float4 b = ((const float4*)src)[1];
  BF tmp[8];
  tmp[0] = f2b(a.x); tmp[1] = f2b(a.y); tmp[2] = f2b(a.z); tmp[3] = f2b(a.w);
  tmp[4] = f2b(b.x); tmp[5] = f2b(b.y); tmp[6] = f2b(b.z); tmp[7] = f2b(b.w);
  *(bf16x8*)(Wkv + (size_t)r * 256 + c8 * 8) = *(bf16x8*)tmp;
  if (u < 512) bkv[u] = ((u & 1) ? bv : bk)[u >> 1];
}

// ---------------------------------------------------------------------------
// rel-bias kernel: one thread per (window w, l=i*4+j). out[w*128 + p*16 + l], f32
// ---------------------------------------------------------------------------
__global__ void __launch_bounds__(256) bias_kernel(
    const float* __restrict__ s_pos, const float* __restrict__ x_pos,
    const float* __restrict__ pw1, const float* __restrict__ pb1,
    const float* __restrict__ bn_g, const float* __restrict__ bn_b,
    const float* __restrict__ bn_m, const float* __restrict__ bn_v,
    const float* __restrict__ pw2, const float* __restrict__ pb2,
    float* __restrict__ out) {
  int gid = blockIdx.x * 256 + threadIdx.x;   // [0, 16384*16)
  int w = gid >> 4, l = gid & 15;
  int b = w >> 12, wi = w & 4095;
  int i = l >> 2, j = l & 3;
  int e0 = i, e1 = 4 + i;
  float sp0 = s_pos[(((size_t)b * 2 + (e0 & 1)) * 4096 + wi) * 4 + (e0 >> 1)];
  float sp1 = s_pos[(((size_t)b * 2 + (e1 & 1)) * 4096 + wi) * 4 + (e1 >> 1)];
  float xp0 = x_pos[((size_t)b * 16384 + j * 4096 + wi) * 2 + 0];
  float xp1 = x_pos[((size_t)b * 16384 + j * 4096 + wi) * 2 + 1];
  float r0 = sp0 - xp0, r1 = sp1 - xp1;
  float acc[8];
#pragma unroll
  for (int p = 0; p < 8; ++p) acc[p] = pb2[p];
#pragma unroll
  for (int o = 0; o < 16; ++o) {
    float t = pw1[o * 2 + 0] * r0 + pw1[o * 2 + 1] * r1 + pb1[o];
    float sc = bn_g[o] / sqrtf(bn_v[o] + 1e-5f);
    t = (t - bn_m[o]) * sc + bn_b[o];
    t = fmaxf(t, 0.0f);
#pragma unroll
    for (int p = 0; p < 8; ++p) acc[p] += pw2[p * 16 + o] * t;
  }
#pragma unroll
  for (int p = 0; p < 8; ++p) out[(size_t)w * 128 + p * 16 + l] = acc[p];
}

// ---------------------------------------------------------------------------
// TN bf16 MFMA GEMM with 2-phase prefetch (double-buffered LDS), templated A
// dtype (float -> reg-staged+converted, BF -> global_load_lds direct).
// C[m,n] = epi(sum_k A[m,k]*Bw[n,k] + bias[n]).  128x128 tile, BK=64,
// 4 waves 2x2, 16x16x32 MFMA. Bijective XCD swizzle (grid always %8==0).
// ---------------------------------------------------------------------------
enum { EPI_NONE = 0, EPI_RES = 1, EPI_GELU = 2 };

template <int EPI, typename AT, typename RT, typename CT>
__global__ void __launch_bounds__(256, 2) gemm_tn(
    const AT* __restrict__ A, const BF* __restrict__ Bw,
    const float* __restrict__ bias, const RT* __restrict__ Res,
    CT* __restrict__ C, int M, int N, int K) {
  constexpr bool F32A = __is_same(AT, float);
  alignas(16) __shared__ BF As[2][8][128][8];
  alignas(16) __shared__ BF Bs[2][8][128][8];
  const int ntiles = N >> 7;
  const int cpx = gridDim.x >> 3;
  const int bid = blockIdx.x;
  const int swz = (bid & 7) * cpx + (bid >> 3);   // XCD-chunked, bijective
  const int mt = swz / ntiles, nt = swz % ntiles;
  const int row0 = mt << 7, col0 = nt << 7;
  const int t = threadIdx.x;
  const int wave = t >> 6, lane = t & 63;
  const int wr = wave >> 1, wc = wave & 1;
  const int sm = t & 127;      // staging row within tile
  const int skc = t >> 7;      // staging k-chunk parity
  f32x4 acc[4][4] = {};
  const int NT = K >> 6;
  float4 ar[4][2];

  auto stageB = [&](int kt, int dbuf) {
#pragma unroll
    for (int i = 0; i < 4; ++i) {
      const int kc = i * 2 + skc;
      gld_lds16(Bw + (size_t)(col0 + sm) * K + kt * 64 + kc * 8,
                &Bs[dbuf][0][0][0] + (size_t)(i * 256 + wave * 64) * 8);
    }
  };
  auto loadA = [&](int kt) {
    if constexpr (F32A) {
#pragma unroll
      for (int i = 0; i < 4; ++i) {
        const int kc = i * 2 + skc;
        const float* src = A + (size_t)(row0 + sm) * K + kt * 64 + kc * 8;
        ar[i][0] = ((const float4*)src)[0];
        ar[i][1] = ((const float4*)src)[1];
      }
    }
  };
  auto writeA = [&](int dbuf) {
    if constexpr (F32A) {
#pragma unroll
      for (int i = 0; i < 4; ++i) {
        const int kc = i * 2 + skc;
        BF tmp[8];
        tmp[0] = f2b(ar[i][0].x); tmp[1] = f2b(ar[i][0].y);
        tmp[2] = f2b(ar[i][0].z); tmp[3] = f2b(ar[i][0].w);
        tmp[4] = f2b(ar[i][1].x); tmp[5] = f2b(ar[i][1].y);
        tmp[6] = f2b(ar[i][1].z); tmp[7] = f2b(ar[i][1].w);
        *(bf16x8*)(&As[dbuf][kc][sm][0]) = *(bf16x8*)tmp;
      }
    }
  };
  auto stageA_bf = [&](int kt, int dbuf) {
    if constexpr (!F32A) {
#pragma unroll
      for (int i = 0; i < 4; ++i) {
        const int kc = i * 2 + skc;
        gld_lds16((const BF*)A + (size_t)(row0 + sm) * K + kt * 64 + kc * 8,
                  &As[dbuf][0][0][0] + (size_t)(i * 256 + wave * 64) * 8);
      }
    }
  };
  auto compute = [&](int dbuf) {
#pragma unroll
    for (int kk = 0; kk < 2; ++kk) {
      const int chunk = kk * 4 + (lane >> 4);
      const int rl = lane & 15;
      bf16x8 af[4], bfr[4];
#pragma unroll
      for (int mi = 0; mi < 4; ++mi)
        af[mi] = *(const bf16x8*)(&As[dbuf][chunk][wr * 64 + mi * 16 + rl][0]);
#pragma unroll
      for (int ni = 0; ni < 4; ++ni)
        bfr[ni] = *(const bf16x8*)(&Bs[dbuf][chunk][wc * 64 + ni * 16 + rl][0]);
#pragma unroll
      for (int mi = 0; mi < 4; ++mi)
#pragma unroll
        for (int ni = 0; ni < 4; ++ni)
          acc[mi][ni] = __builtin_amdgcn_mfma_f32_16x16x32_bf16(
              af[mi], bfr[ni], acc[mi][ni], 0, 0, 0);
    }
  };

  // prologue: stage tile 0 into buffer 0
  loadA(0); stageA_bf(0, 0); stageB(0, 0); writeA(0);
  __syncthreads();
  int cur = 0;
  for (int kt = 0; kt < NT; ++kt) {
    const bool more = (kt + 1 < NT);
    if (more) {           // issue next-tile loads before computing current
      loadA(kt + 1);
      stageA_bf(kt + 1, cur ^ 1);
      stageB(kt + 1, cur ^ 1);
    }
    compute(cur);
    if (more) writeA(cur ^ 1);  // f32 path: LDS write after MFMA (hides latency)
    __syncthreads();
    cur ^= 1;
  }

  // epilogue: D layout col = lane&15, row = (lane>>4)*4 + r (m89-verified)
  const int rl = lane & 15, rg = lane >> 4;
#pragma unroll
  for (int mi = 0; mi < 4; ++mi) {
#pragma unroll
    for (int ni = 0; ni < 4; ++ni) {
      const int col = col0 + wc * 64 + ni * 16 + rl;
      const float bcol = bias[col];
#pragma unroll
      for (int r = 0; r < 4; ++r) {
        const int row = row0 + wr * 64 + mi * 16 + rg * 4 + r;
        float v = acc[mi][ni][r] + bcol;
        if constexpr (EPI == EPI_GELU)
          v = 0.5f * v * (1.0f + erff(v * 0.70710678118654752f));
        if constexpr (EPI == EPI_RES) {
          if constexpr (__is_same(RT, float))
            v += Res[(size_t)row * N + col];
          else
            v += b2f(Res[(size_t)row * N + col]);
        }
        if constexpr (__is_same(CT, float))
          C[(size_t)row * N + col] = v;
        else
          C[(size_t)row * N + col] = f2b(v);
      }
    }
  }
}

// ---------------------------------------------------------------------------
// Windowed attention v2. Block = (b, hi, head-pair p, c-quarter cq):
// 64 windows x 2 heads. Q staged via LDS (coalesced 128B global reads,
// XOR-chunk swizzle). KV interleaved (k,v adjacent) -> dword loads.
//   q[w,nh,qi,hd] = Qproj[b, nh*2048+hd*64+qi*16+hi, cq*64+c]
//   k/v[w,nh,kj,hd] = KV[(b*16384+kj*4096+wi)*512 + 2*(nh*32+hd) + {0,1}]
//   O[b, qi*4096+wi, nh*32+hd]
// ---------------------------------------------------------------------------
__global__ void __launch_bounds__(256) attn_kernel(
    const BF* __restrict__ Q, const BF* __restrict__ KV,
    const float* __restrict__ bias, BF* __restrict__ O) {
  const int bid = blockIdx.x;
  const int cq = bid & 3, p = (bid >> 2) & 3, hi = (bid >> 4) & 15, b = bid >> 8;
  const int t = threadIdx.x;
  const float SCALE = 0.17677669529663689f;  // 32^-0.5
  __shared__ BF Qlds[256][64];  // elem (r,c) at col ((c>>3)^(r&7))*8 + (c&7)

  {  // stage Q: rows r = h*128+qi*32+hd, cols c in [0,64)
    const int rloc = t >> 3, cg = t & 7;
#pragma unroll
    for (int it = 0; it < 8; ++it) {
      const int r = it * 32 + rloc;
      const int h = r >> 7, qi = (r >> 5) & 3, hd = r & 31;
      const int nh = p * 2 + h;
      const int l = nh * 2048 + hd * 64 + qi * 16 + hi;
      bf16x8 v = *(const bf16x8*)(Q + ((size_t)b * 16384 + l) * 256 + cq * 64 + cg * 8);
      *(bf16x8*)(&Qlds[r][(cg ^ (r & 7)) * 8]) = v;
    }
  }
  __syncthreads();

  const int g = t >> 5, hd = t & 31;
  const int wbase = hi * 256 + cq * 64;
  for (int c8 = 0; c8 < 8; ++c8) {
    const int c = g * 8 + c8;
    const int wi = wbase + c;
    const int w = b * 4096 + wi;
    // bias: lanes 0-15 hold h=0 pairs, 16-31 hold h=1 pairs (coalesced 128B)
    const float bias_l = bias[(size_t)w * 128 + (p * 2 + (hd >> 4)) * 16 + (hd & 15)];
#pragma unroll
    for (int h = 0; h < 2; ++h) {
      const int nh = p * 2 + h;
      float qv[4];
#pragma unroll
      for (int qi = 0; qi < 4; ++qi) {
        const int r = h * 128 + qi * 32 + hd;
        qv[qi] = b2f(Qlds[r][(((c >> 3) ^ (hd & 7)) << 3) | (c & 7)]) * SCALE;
      }
      float kf[4], vf[4];
#pragma unroll
      for (int kj = 0; kj < 4; ++kj) {
        const unsigned int kvp = *(const unsigned int*)(
            KV + ((size_t)(b * 16384 + kj * 4096 + wi)) * 512 + ((nh * 32 + hd) << 1));
        kf[kj] = __uint_as_float(kvp << 16);
        vf[kj] = __uint_as_float(kvp & 0xffff0000u);
      }
      float sc[16];
#pragma unroll
      for (int qi = 0; qi < 4; ++qi)
#pragma unroll
        for (int kj = 0; kj < 4; ++kj) {
          float pp = qv[qi] * kf[kj];
          pp += __shfl_xor(pp, 1);
          pp += __shfl_xor(pp, 2);
          pp += __shfl_xor(pp, 4);
          pp += __shfl_xor(pp, 8);
          pp += __shfl_xor(pp, 16);
          sc[qi * 4 + kj] = pp;
        }
#pragma unroll
      for (int idx = 0; idx < 16; ++idx)
        sc[idx] += __shfl(bias_l, (t & 32) + h * 16 + idx);
#pragma unroll
      for (int qi = 0; qi < 4; ++qi) {
        float s0 = sc[qi * 4], s1 = sc[qi * 4 + 1], s2 = sc[qi * 4 + 2], s3 = sc[qi * 4 + 3];
        float mx = fmaxf(fmaxf(s0, s1), fmaxf(s2, s3));
        float e0 = __expf(s0 - mx), e1 = __expf(s1 - mx);
        float e2 = __expf(s2 - mx), e3 = __expf(s3 - mx);
        float inv = 1.0f / (e0 + e1 + e2 + e3);
        float o = (e0 * vf[0] + e1 * vf[1] + e2 * vf[2] + e3 * vf[3]) * inv;
        O[((size_t)b * 16384 + qi * 4096 + wi) * 256 + nh * 32 + hd] = f2b(o);
      }
    }
  }
}

// ---------------------------------------------------------------------------
// LayerNorm over C=256: one 64-lane wave per row, 4 bf16 per lane.
// ---------------------------------------------------------------------------
__global__ void __launch_bounds__(256) ln_kernel(
    const BF* __restrict__ S1, const float* __restrict__ g,
    const float* __restrict__ be, BF* __restrict__ Nout) {
  const int wave = threadIdx.x >> 6, lane = threadIdx.x & 63;
  const size_t row = (size_t)blockIdx.x * 4 + wave;
  BF4 d = *(const BF4*)(S1 + row * 256 + lane * 4);
  float x[4] = {b2f(d.v[0]), b2f(d.v[1]), b2f(d.v[2]), b2f(d.v[3])};
  float s = x[0] + x[1] + x[2] + x[3];
  float sq = x[0] * x[0] + x[1] * x[1] + x[2] * x[2] + x[3] * x[3];
#pragma unroll
  for (int m = 1; m <= 32; m <<= 1) {
    s += __shfl_xor(s, m);
    sq += __shfl_xor(sq, m);
  }
  const float mean = s * 0.00390625f;
  const float var = sq * 0.00390625f - mean * mean;
  const float rstd = 1.0f / sqrtf(var + 1e-5f);
  BF4 o;
#pragma unroll
  for (int jj = 0; jj < 4; ++jj) {
    float nv = (x[jj] - mean) * rstd * g[lane * 4 + jj] + be[lane * 4 + jj];
    o.v[jj] = f2b(nv);
  }
  *(BF4*)(Nout + row * 256 + lane * 4) = o;
}

// ---------------------------------------------------------------------------
// ws layout (bytes):
//   [0,          8388608)   bias f32 (nW*128)
//   [8388608,    41943040)  Qproj bf16 -> reused as LN output after attn
//   [41943040,  109051904)  KV interleaved bf16 (65536 x 512) -> H2 after attn
//   [109051904, 142606336)  S1 bf16
//   [142606336, ...)        bf16 weights Wq,Wo (128KB), Wkv (256KB),
//                           mw1,mw2 (512KB), bkv f32 (2KB)   (total ~144MB)
// d_out doubles as bf16 attn-output staging (consumed by Wo-GEMM, then
// overwritten with final f32 by MLP2).
// ---------------------------------------------------------------------------
extern "C" void kernel_launch(void* const* d_in, const int* in_sizes, int n_in,
                              void* d_out, int out_size, void* d_ws, size_t ws_size,
                              hipStream_t stream) {
  const float* s     = (const float*)d_in[0];
  const float* x     = (const float*)d_in[1];
  const float* s_pos = (const float*)d_in[2];
  const float* x_pos = (const float*)d_in[3];
  const float* Wq = (const float*)d_in[4];  const float* bq = (const float*)d_in[5];
  const float* Wk = (const float*)d_in[6];  const float* bk = (const float*)d_in[7];
  const float* Wv = (const float*)d_in[8];  const float* bv = (const float*)d_in[9];
  const float* Wo = (const float*)d_in[10]; const float* bo = (const float*)d_in[11];
  const float* pw1 = (const float*)d_in[12]; const float* pb1 = (const float*)d_in[13];
  const float* bn_g = (const float*)d_in[14]; const float* bn_b = (const float*)d_in[15];
  const float* bn_m = (const float*)d_in[16]; const float* bn_v = (const float*)d_in[17];
  const float* pw2 = (const float*)d_in[18]; const float* pb2 = (const float*)d_in[19];
  const float* ln_g = (const float*)d_in[20]; const float* ln_b = (const float*)d_in[21];
  const float* mw1 = (const float*)d_in[22]; const float* mb1 = (const float*)d_in[23];
  const float* mw2 = (const float*)d_in[24]; const float* mb2 = (const float*)d_in[25];

  char* ws = (char*)d_ws;
  float* biasb = (float*)ws;
  BF* Qw   = (BF*)(ws + 8388608);
  BF* KVw  = (BF*)(ws + 41943040);
  BF* S1   = (BF*)(ws + 109051904);
  BF* Wq_bf  = (BF*)(ws + 142606336);
  BF* Wo_bf  = (BF*)(ws + 142737408);
  BF* Wkv_bf = (BF*)(ws + 142868480);
  BF* mw1_bf = (BF*)(ws + 143130624);
  BF* mw2_bf = (BF*)(ws + 143654912);
  float* bkv = (float*)(ws + 144179200);
  BF* Nw = Qw;            // LN output reuses Q region (free after attn)
  BF* H2 = KVw;           // MLP hidden reuses KV region (free after attn)
  BF* ObBF = (BF*)d_out;  // attn output staged bf16 inside d_out
  float* Of = (float*)d_out;

  cvt_kernel<<<64, 256, 0, stream>>>(Wq, Wq_bf, 16384);
  cvt_kernel<<<64, 256, 0, stream>>>(Wo, Wo_bf, 16384);
  cvt_kernel<<<256, 256, 0, stream>>>(mw1, mw1_bf, 65536);
  cvt_kernel<<<256, 256, 0, stream>>>(mw2, mw2_bf, 65536);
  cvt_kv_kernel<<<64, 256, 0, stream>>>(Wk, Wv, bk, bv, Wkv_bf, bkv);
  bias_kernel<<<1024, 256, 0, stream>>>(s_pos, x_pos, pw1, pb1, bn_g, bn_b,
                                        bn_m, bn_v, pw2, pb2, biasb);

  gemm_tn<EPI_NONE, float, float, BF><<<1024, 256, 0, stream>>>(
      s, Wq_bf, bq, nullptr, Qw, 65536, 256, 256);
  gemm_tn<EPI_NONE, float, float, BF><<<2048, 256, 0, stream>>>(
      x, Wkv_bf, bkv, nullptr, KVw, 65536, 512, 256);
  attn_kernel<<<1024, 256, 0, stream>>>(Qw, KVw, biasb, ObBF);
  gemm_tn<EPI_RES, BF, float, BF><<<1024, 256, 0, stream>>>(
      ObBF, Wo_bf, bo, s, S1, 65536, 256, 256);
  ln_kernel<<<16384, 256, 0, stream>>>(S1, ln_g, ln_b, Nw);
  for (int h = 0; h < 2; ++h) {
    const size_t ro = (size_t)h * 32768;
    gemm_tn<EPI_GELU, BF, float, BF><<<2048, 256, 0, stream>>>(
        Nw + ro * 256, mw1_bf, mb1, nullptr, H2, 32768, 1024, 256);
    gemm_tn<EPI_RES, BF, BF, float><<<512, 256, 0, stream>>>(
        H2, mw2_bf, mb2, S1 + ro * 256, Of + ro * 256, 32768, 256, 1024);
  }
}

// Round 4
// 419.859 us; speedup vs baseline: 1.1630x; 1.0913x over previous
//
#include <hip/hip_runtime.h>
#include <hip/hip_bf16.h>
#include <math.h>

typedef __hip_bfloat16 BF;
typedef __bf16 bf16x8 __attribute__((ext_vector_type(8)));
typedef float f32x4 __attribute__((ext_vector_type(4)));

struct alignas(8) BF4 { BF v[4]; };
struct alignas(16) BF8 { BF v[8]; };

static __device__ __forceinline__ float b2f(BF x) { return __bfloat162float(x); }
static __device__ __forceinline__ BF f2b(float x) { return __float2bfloat16(x); }

// async global->LDS, 16B per lane; LDS dest = wave-uniform base (+lane*16 implicit)
static __device__ __forceinline__ void gld_lds16(const void* g, void* l) {
  __builtin_amdgcn_global_load_lds(
      (const __attribute__((address_space(1))) unsigned int*)g,
      (__attribute__((address_space(3))) unsigned int*)l, 16, 0, 0);
}

// ---------------------------------------------------------------------------
// f32 -> bf16 convert, 4 elements/thread, grid-stride
// ---------------------------------------------------------------------------
__global__ void __launch_bounds__(256) cvt_kernel(
    const float* __restrict__ in, BF* __restrict__ out, int n4) {
  for (int i = blockIdx.x * 256 + threadIdx.x; i < n4; i += gridDim.x * 256) {
    float4 v = ((const float4*)in)[i];
    BF4 o;
    o.v[0] = f2b(v.x); o.v[1] = f2b(v.y); o.v[2] = f2b(v.z); o.v[3] = f2b(v.w);
    ((BF4*)out)[i] = o;
  }
}

// concat bk||bv -> bkv (f32), 2 blocks x 256
__global__ void __launch_bounds__(256) bkv_kernel(
    const float* __restrict__ bk, const float* __restrict__ bv,
    float* __restrict__ bkv) {
  int i = blockIdx.x * 256 + threadIdx.x;
  bkv[i] = (i < 256) ? bk[i] : bv[i - 256];
}

// ---------------------------------------------------------------------------
// rel-bias kernel: one thread per (window w, l=qi*4+kj). out[w*128+nh*16+l], f32
// ---------------------------------------------------------------------------
__global__ void __launch_bounds__(256) bias_kernel(
    const float* __restrict__ s_pos, const float* __restrict__ x_pos,
    const float* __restrict__ pw1, const float* __restrict__ pb1,
    const float* __restrict__ bn_g, const float* __restrict__ bn_b,
    const float* __restrict__ bn_m, const float* __restrict__ bn_v,
    const float* __restrict__ pw2, const float* __restrict__ pb2,
    float* __restrict__ out) {
  int gid = blockIdx.x * 256 + threadIdx.x;   // [0, 16384*16)
  int w = gid >> 4, l = gid & 15;
  int b = w >> 12, wi = w & 4095;
  int i = l >> 2, j = l & 3;
  int e0 = i, e1 = 4 + i;
  float sp0 = s_pos[(((size_t)b * 2 + (e0 & 1)) * 4096 + wi) * 4 + (e0 >> 1)];
  float sp1 = s_pos[(((size_t)b * 2 + (e1 & 1)) * 4096 + wi) * 4 + (e1 >> 1)];
  float xp0 = x_pos[((size_t)b * 16384 + j * 4096 + wi) * 2 + 0];
  float xp1 = x_pos[((size_t)b * 16384 + j * 4096 + wi) * 2 + 1];
  float r0 = sp0 - xp0, r1 = sp1 - xp1;
  float acc[8];
#pragma unroll
  for (int p = 0; p < 8; ++p) acc[p] = pb2[p];
#pragma unroll
  for (int o = 0; o < 16; ++o) {
    float t = pw1[o * 2 + 0] * r0 + pw1[o * 2 + 1] * r1 + pb1[o];
    float sc = bn_g[o] / sqrtf(bn_v[o] + 1e-5f);
    t = (t - bn_m[o]) * sc + bn_b[o];
    t = fmaxf(t, 0.0f);
#pragma unroll
    for (int p = 0; p < 8; ++p) acc[p] += pw2[p * 16 + o] * t;
  }
#pragma unroll
  for (int p = 0; p < 8; ++p) out[(size_t)w * 128 + p * 16 + l] = acc[p];
}

// ---------------------------------------------------------------------------
// TN bf16 MFMA GEMM with 2-phase prefetch (double-buffered LDS), templated A
// dtype (float -> reg-staged+converted, BF -> global_load_lds direct).
// C[m,n] = epi(sum_k A[m,k]*Bw[n,k] + bias[n]).  128x128 tile, BK=64,
// 4 waves 2x2, 16x16x32 MFMA. Bijective XCD swizzle (grid always %8==0).
// ---------------------------------------------------------------------------
enum { EPI_NONE = 0, EPI_RES = 1, EPI_GELU = 2 };

template <int EPI, typename AT, typename RT, typename CT>
__global__ void __launch_bounds__(256, 2) gemm_tn(
    const AT* __restrict__ A, const BF* __restrict__ Bw,
    const float* __restrict__ bias, const RT* __restrict__ Res,
    CT* __restrict__ C, int M, int N, int K) {
  constexpr bool F32A = __is_same(AT, float);
  alignas(16) __shared__ BF As[2][8][128][8];
  alignas(16) __shared__ BF Bs[2][8][128][8];
  const int ntiles = N >> 7;
  const int cpx = gridDim.x >> 3;
  const int bid = blockIdx.x;
  const int swz = (bid & 7) * cpx + (bid >> 3);   // XCD-chunked, bijective
  const int mt = swz / ntiles, nt = swz % ntiles;
  const int row0 = mt << 7, col0 = nt << 7;
  const int t = threadIdx.x;
  const int wave = t >> 6, lane = t & 63;
  const int wr = wave >> 1, wc = wave & 1;
  const int sm = t & 127;      // staging row within tile
  const int skc = t >> 7;      // staging k-chunk parity
  f32x4 acc[4][4] = {};
  const int NT = K >> 6;
  float4 ar[4][2];

  auto stageB = [&](int kt, int dbuf) {
#pragma unroll
    for (int i = 0; i < 4; ++i) {
      const int kc = i * 2 + skc;
      gld_lds16(Bw + (size_t)(col0 + sm) * K + kt * 64 + kc * 8,
                &Bs[dbuf][0][0][0] + (size_t)(i * 256 + wave * 64) * 8);
    }
  };
  auto loadA = [&](int kt) {
    if constexpr (F32A) {
#pragma unroll
      for (int i = 0; i < 4; ++i) {
        const int kc = i * 2 + skc;
        const float* src = A + (size_t)(row0 + sm) * K + kt * 64 + kc * 8;
        ar[i][0] = ((const float4*)src)[0];
        ar[i][1] = ((const float4*)src)[1];
      }
    }
  };
  auto writeA = [&](int dbuf) {
    if constexpr (F32A) {
#pragma unroll
      for (int i = 0; i < 4; ++i) {
        const int kc = i * 2 + skc;
        BF tmp[8];
        tmp[0] = f2b(ar[i][0].x); tmp[1] = f2b(ar[i][0].y);
        tmp[2] = f2b(ar[i][0].z); tmp[3] = f2b(ar[i][0].w);
        tmp[4] = f2b(ar[i][1].x); tmp[5] = f2b(ar[i][1].y);
        tmp[6] = f2b(ar[i][1].z); tmp[7] = f2b(ar[i][1].w);
        *(bf16x8*)(&As[dbuf][kc][sm][0]) = *(bf16x8*)tmp;
      }
    }
  };
  auto stageA_bf = [&](int kt, int dbuf) {
    if constexpr (!F32A) {
#pragma unroll
      for (int i = 0; i < 4; ++i) {
        const int kc = i * 2 + skc;
        gld_lds16((const BF*)A + (size_t)(row0 + sm) * K + kt * 64 + kc * 8,
                  &As[dbuf][0][0][0] + (size_t)(i * 256 + wave * 64) * 8);
      }
    }
  };
  auto compute = [&](int dbuf) {
#pragma unroll
    for (int kk = 0; kk < 2; ++kk) {
      const int chunk = kk * 4 + (lane >> 4);
      const int rl = lane & 15;
      bf16x8 af[4], bfr[4];
#pragma unroll
      for (int mi = 0; mi < 4; ++mi)
        af[mi] = *(const bf16x8*)(&As[dbuf][chunk][wr * 64 + mi * 16 + rl][0]);
#pragma unroll
      for (int ni = 0; ni < 4; ++ni)
        bfr[ni] = *(const bf16x8*)(&Bs[dbuf][chunk][wc * 64 + ni * 16 + rl][0]);
#pragma unroll
      for (int mi = 0; mi < 4; ++mi)
#pragma unroll
        for (int ni = 0; ni < 4; ++ni)
          acc[mi][ni] = __builtin_amdgcn_mfma_f32_16x16x32_bf16(
              af[mi], bfr[ni], acc[mi][ni], 0, 0, 0);
    }
  };

  loadA(0); stageA_bf(0, 0); stageB(0, 0); writeA(0);
  __syncthreads();
  int cur = 0;
  for (int kt = 0; kt < NT; ++kt) {
    const bool more = (kt + 1 < NT);
    if (more) {
      loadA(kt + 1);
      stageA_bf(kt + 1, cur ^ 1);
      stageB(kt + 1, cur ^ 1);
    }
    compute(cur);
    if (more) writeA(cur ^ 1);
    __syncthreads();
    cur ^= 1;
  }

  // epilogue: D layout col = lane&15, row = (lane>>4)*4 + r (m89-verified)
  const int rl = lane & 15, rg = lane >> 4;
#pragma unroll
  for (int mi = 0; mi < 4; ++mi) {
#pragma unroll
    for (int ni = 0; ni < 4; ++ni) {
      const int col = col0 + wc * 64 + ni * 16 + rl;
      const float bcol = bias[col];
#pragma unroll
      for (int r = 0; r < 4; ++r) {
        const int row = row0 + wr * 64 + mi * 16 + rg * 4 + r;
        float v = acc[mi][ni][r] + bcol;
        if constexpr (EPI == EPI_GELU)
          v = 0.5f * v * (1.0f + erff(v * 0.70710678118654752f));
        if constexpr (EPI == EPI_RES) {
          if constexpr (__is_same(RT, float))
            v += Res[(size_t)row * N + col];
          else
            v += b2f(Res[(size_t)row * N + col]);
        }
        if constexpr (__is_same(CT, float))
          C[(size_t)row * N + col] = v;
        else
          C[(size_t)row * N + col] = f2b(v);
      }
    }
  }
}

// ---------------------------------------------------------------------------
// Q-projection GEMM writing attention layout directly:
//   Qa[b][wi][nh][qi][hd] = (s @ Wq^T + bq)[b, l, c] * SCALE
//   with l = nh*2048 + hd*64 + qi*16 + hi, wi = hi*256 + c.
// M-tiling permuted: tile mt = ((b*8+nh)*4+qi)*4+hp; tile-row i = hil*32+hd
// (hil in [0,4), hi = hp*4+hil). Epilogue: 4 consecutive-hd accs -> one 8B
// store; wave covers full 64B lines via L2 write-combine.
// ---------------------------------------------------------------------------
__global__ void __launch_bounds__(256, 2) gemm_q(
    const float* __restrict__ A, const BF* __restrict__ Bw,
    const float* __restrict__ bias, BF* __restrict__ Qa) {
  constexpr int K = 256;
  alignas(16) __shared__ BF As[2][8][128][8];
  alignas(16) __shared__ BF Bs[2][8][128][8];
  const int cpx = gridDim.x >> 3;
  const int bid = blockIdx.x;
  const int swz = (bid & 7) * cpx + (bid >> 3);
  const int mt = swz >> 1, nt = swz & 1;
  const int hp = mt & 3, qi = (mt >> 2) & 3, nh = (mt >> 4) & 7, bb = mt >> 7;
  const int col0 = nt << 7;
  const int t = threadIdx.x;
  const int wave = t >> 6, lane = t & 63;
  const int wr = wave >> 1, wc = wave & 1;
  const int sm = t & 127;
  const int skc = t >> 7;
  // permuted A row for tile row sm
  const size_t grow = (size_t)bb * 16384 + nh * 2048 + (size_t)(sm & 31) * 64 +
                      qi * 16 + hp * 4 + (sm >> 5);
  f32x4 acc[4][4] = {};
  float4 ar[4][2];

  auto stageB = [&](int kt, int dbuf) {
#pragma unroll
    for (int i = 0; i < 4; ++i) {
      const int kc = i * 2 + skc;
      gld_lds16(Bw + (size_t)(col0 + sm) * K + kt * 64 + kc * 8,
                &Bs[dbuf][0][0][0] + (size_t)(i * 256 + wave * 64) * 8);
    }
  };
  auto loadA = [&](int kt) {
#pragma unroll
    for (int i = 0; i < 4; ++i) {
      const int kc = i * 2 + skc;
      const float* src = A + grow * K + kt * 64 + kc * 8;
      ar[i][0] = ((const float4*)src)[0];
      ar[i][1] = ((const float4*)src)[1];
    }
  };
  auto writeA = [&](int dbuf) {
#pragma unroll
    for (int i = 0; i < 4; ++i) {
      const int kc = i * 2 + skc;
      BF tmp[8];
      tmp[0] = f2b(ar[i][0].x); tmp[1] = f2b(ar[i][0].y);
      tmp[2] = f2b(ar[i][0].z); tmp[3] = f2b(ar[i][0].w);
      tmp[4] = f2b(ar[i][1].x); tmp[5] = f2b(ar[i][1].y);
      tmp[6] = f2b(ar[i][1].z); tmp[7] = f2b(ar[i][1].w);
      *(bf16x8*)(&As[dbuf][kc][sm][0]) = *(bf16x8*)tmp;
    }
  };
  auto compute = [&](int dbuf) {
#pragma unroll
    for (int kk = 0; kk < 2; ++kk) {
      const int chunk = kk * 4 + (lane >> 4);
      const int rl = lane & 15;
      bf16x8 af[4], bfr[4];
#pragma unroll
      for (int mi = 0; mi < 4; ++mi)
        af[mi] = *(const bf16x8*)(&As[dbuf][chunk][wr * 64 + mi * 16 + rl][0]);
#pragma unroll
      for (int ni = 0; ni < 4; ++ni)
        bfr[ni] = *(const bf16x8*)(&Bs[dbuf][chunk][wc * 64 + ni * 16 + rl][0]);
#pragma unroll
      for (int mi = 0; mi < 4; ++mi)
#pragma unroll
        for (int ni = 0; ni < 4; ++ni)
          acc[mi][ni] = __builtin_amdgcn_mfma_f32_16x16x32_bf16(
              af[mi], bfr[ni], acc[mi][ni], 0, 0, 0);
    }
  };

  loadA(0); stageB(0, 0); writeA(0);
  __syncthreads();
  int cur = 0;
  for (int kt = 0; kt < 4; ++kt) {
    const bool more = (kt + 1 < 4);
    if (more) { loadA(kt + 1); stageB(kt + 1, cur ^ 1); }
    compute(cur);
    if (more) writeA(cur ^ 1);
    __syncthreads();
    cur ^= 1;
  }

  const int rl = lane & 15, rg = lane >> 4;
  const float SCALE = 0.17677669529663689f;  // 32^-0.5
#pragma unroll
  for (int mi = 0; mi < 4; ++mi) {
#pragma unroll
    for (int ni = 0; ni < 4; ++ni) {
      const int col = col0 + wc * 64 + ni * 16 + rl;
      const float bcol = bias[col];
      const int i0 = wr * 64 + mi * 16 + rg * 4;
      const int hd = i0 & 31, hil = i0 >> 5;
      const int wi = (hp * 4 + hil) * 256 + col;
      BF4 pk;
#pragma unroll
      for (int r = 0; r < 4; ++r)
        pk.v[r] = f2b((acc[mi][ni][r] + bcol) * SCALE);
      *(BF4*)(Qa + ((((size_t)bb * 4096 + wi) * 8 + nh) * 128 + qi * 32 + hd)) = pk;
    }
  }
}

// ---------------------------------------------------------------------------
// Windowed attention v3: no LDS, no QK shuffles. 16-lane group per (w,nh),
// lane = qi*4+kj. q from Qa (hd-contig, pre-scaled), k/v from KV512
// (row l_x = kj*4096+wi; cols [0:256)=K, [256:512)=V; hd-contig 64B runs).
// Dot over hd lane-local; softmax in lane-quads (4 shfl); PV lane-local on
// hd-octet kj with p all-gathered (3 shfl).
// ---------------------------------------------------------------------------
__global__ void __launch_bounds__(256) attn_kernel(
    const BF* __restrict__ Qa, const BF* __restrict__ KV,
    const float* __restrict__ biasb, BF* __restrict__ O) {
  const int t = threadIdx.x;
  const int g = t >> 4, l16 = t & 15;
  const int qi = l16 >> 2, kj = l16 & 3;
  const int w = (blockIdx.x << 1) | (g >> 3);
  const int nh = g & 7;
  const int b = w >> 12, wi = w & 4095;

  const uint4* qp = (const uint4*)(Qa + ((((size_t)b * 4096 + wi) * 8 + nh) * 128 + qi * 32));
  uint4 qv[4] = {qp[0], qp[1], qp[2], qp[3]};
  const uint4* kp = (const uint4*)(KV + ((size_t)b * 16384 + kj * 4096 + wi) * 512 + nh * 32);
  uint4 kv[4] = {kp[0], kp[1], kp[2], kp[3]};
  const float bias_l = biasb[(size_t)w * 128 + nh * 16 + l16];
  // V loads: independent of softmax -> issue early. Row j = kj^d, octet = kj.
  const BF* vbase = KV + (size_t)b * 16384 * 512 + 256 + nh * 32 + kj * 8;
  uint4 vv[4];
#pragma unroll
  for (int d = 0; d < 4; ++d)
    vv[d] = *(const uint4*)(vbase + ((size_t)((kj ^ d) * 4096 + wi)) * 512);

  float accs[4] = {0.f, 0.f, 0.f, 0.f};
#pragma unroll
  for (int j = 0; j < 4; ++j) {
#pragma unroll
    for (int e = 0; e < 4; ++e) {
      unsigned qe = ((const unsigned*)&qv[j])[e];
      unsigned ke = ((const unsigned*)&kv[j])[e];
      float ql = __uint_as_float(qe << 16);
      float qh = __uint_as_float(qe & 0xffff0000u);
      float kl = __uint_as_float(ke << 16);
      float kh = __uint_as_float(ke & 0xffff0000u);
      accs[e] = fmaf(ql, kl, accs[e]);
      accs[e] = fmaf(qh, kh, accs[e]);
    }
  }
  const float score = accs[0] + accs[1] + accs[2] + accs[3] + bias_l;

  // softmax over kj (lane-quad)
  float mx = fmaxf(score, __shfl_xor(score, 1));
  mx = fmaxf(mx, __shfl_xor(mx, 2));
  float e = __expf(score - mx);
  float sm = e + __shfl_xor(e, 1);
  sm += __shfl_xor(sm, 2);
  float p = e / sm;
  // all-gather p within quad: pd[d] = p of lane kj^d
  float pd[4];
  pd[0] = p;
  pd[1] = __shfl_xor(p, 1);
  pd[2] = __shfl_xor(p, 2);
  pd[3] = __shfl_xor(pd[1], 2);

  float o8[8] = {0.f, 0.f, 0.f, 0.f, 0.f, 0.f, 0.f, 0.f};
#pragma unroll
  for (int d = 0; d < 4; ++d) {
#pragma unroll
    for (int e = 0; e < 4; ++e) {
      unsigned ve = ((const unsigned*)&vv[d])[e];
      o8[e * 2 + 0] = fmaf(pd[d], __uint_as_float(ve << 16), o8[e * 2 + 0]);
      o8[e * 2 + 1] = fmaf(pd[d], __uint_as_float(ve & 0xffff0000u), o8[e * 2 + 1]);
    }
  }
  BF8 ob;
#pragma unroll
  for (int h = 0; h < 8; ++h) ob.v[h] = f2b(o8[h]);
  *(BF8*)(O + ((size_t)b * 16384 + qi * 4096 + wi) * 256 + nh * 32 + kj * 8) = ob;
}

// ---------------------------------------------------------------------------
// LayerNorm over C=256: one 64-lane wave per row, 4 bf16 per lane.
// ---------------------------------------------------------------------------
__global__ void __launch_bounds__(256) ln_kernel(
    const BF* __restrict__ S1, const float* __restrict__ g,
    const float* __restrict__ be, BF* __restrict__ Nout) {
  const int wave = threadIdx.x >> 6, lane = threadIdx.x & 63;
  const size_t row = (size_t)blockIdx.x * 4 + wave;
  BF4 d = *(const BF4*)(S1 + row * 256 + lane * 4);
  float x[4] = {b2f(d.v[0]), b2f(d.v[1]), b2f(d.v[2]), b2f(d.v[3])};
  float s = x[0] + x[1] + x[2] + x[3];
  float sq = x[0] * x[0] + x[1] * x[1] + x[2] * x[2] + x[3] * x[3];
#pragma unroll
  for (int m = 1; m <= 32; m <<= 1) {
    s += __shfl_xor(s, m);
    sq += __shfl_xor(sq, m);
  }
  const float mean = s * 0.00390625f;
  const float var = sq * 0.00390625f - mean * mean;
  const float rstd = 1.0f / sqrtf(var + 1e-5f);
  BF4 o;
#pragma unroll
  for (int jj = 0; jj < 4; ++jj) {
    float nv = (x[jj] - mean) * rstd * g[lane * 4 + jj] + be[lane * 4 + jj];
    o.v[jj] = f2b(nv);
  }
  *(BF4*)(Nout + row * 256 + lane * 4) = o;
}

// ---------------------------------------------------------------------------
// ws layout (bytes):
//   [0,          8388608)   rel-bias f32 (nW*128)
//   [8388608,    41943040)  Qa bf16 [b][wi][nh][qi][hd] -> LN out after attn
//   [41943040,  109051904)  KV512 bf16 (65536 x 512; K|V halves) -> H2 after
//   [109051904, 142606336)  S1 bf16
//   [142606336, ~144.2MB)   bf16 weights Wq,Wo, Wkv(stacked), mw1, mw2; bkv f32
// d_out doubles as bf16 attn-output staging (consumed by Wo-GEMM, then
// overwritten with final f32 by MLP2).
// ---------------------------------------------------------------------------
extern "C" void kernel_launch(void* const* d_in, const int* in_sizes, int n_in,
                              void* d_out, int out_size, void* d_ws, size_t ws_size,
                              hipStream_t stream) {
  const float* s     = (const float*)d_in[0];
  const float* x     = (const float*)d_in[1];
  const float* s_pos = (const float*)d_in[2];
  const float* x_pos = (const float*)d_in[3];
  const float* Wq = (const float*)d_in[4];  const float* bq = (const float*)d_in[5];
  const float* Wk = (const float*)d_in[6];  const float* bk = (const float*)d_in[7];
  const float* Wv = (const float*)d_in[8];  const float* bv = (const float*)d_in[9];
  const float* Wo = (const float*)d_in[10]; const float* bo = (const float*)d_in[11];
  const float* pw1 = (const float*)d_in[12]; const float* pb1 = (const float*)d_in[13];
  const float* bn_g = (const float*)d_in[14]; const float* bn_b = (const float*)d_in[15];
  const float* bn_m = (const float*)d_in[16]; const float* bn_v = (const float*)d_in[17];
  const float* pw2 = (const float*)d_in[18]; const float* pb2 = (const float*)d_in[19];
  const float* ln_g = (const float*)d_in[20]; const float* ln_b = (const float*)d_in[21];
  const float* mw1 = (const float*)d_in[22]; const float* mb1 = (const float*)d_in[23];
  const float* mw2 = (const float*)d_in[24]; const float* mb2 = (const float*)d_in[25];

  char* ws = (char*)d_ws;
  float* biasb = (float*)ws;
  BF* Qa   = (BF*)(ws + 8388608);
  BF* KVw  = (BF*)(ws + 41943040);
  BF* S1   = (BF*)(ws + 109051904);
  BF* Wq_bf  = (BF*)(ws + 142606336);
  BF* Wo_bf  = (BF*)(ws + 142737408);
  BF* Wkv_bf = (BF*)(ws + 142868480);
  BF* mw1_bf = (BF*)(ws + 143130624);
  BF* mw2_bf = (BF*)(ws + 143654912);
  float* bkv = (float*)(ws + 144179200);
  BF* Nw = Qa;            // LN output reuses Qa region (free after attn)
  BF* H2 = KVw;           // MLP hidden reuses KV region (free after attn)
  BF* ObBF = (BF*)d_out;  // attn output staged bf16 inside d_out
  float* Of = (float*)d_out;

  cvt_kernel<<<64, 256, 0, stream>>>(Wq, Wq_bf, 16384);
  cvt_kernel<<<64, 256, 0, stream>>>(Wo, Wo_bf, 16384);
  cvt_kernel<<<64, 256, 0, stream>>>(Wk, Wkv_bf, 16384);
  cvt_kernel<<<64, 256, 0, stream>>>(Wv, Wkv_bf + 65536, 16384);
  cvt_kernel<<<256, 256, 0, stream>>>(mw1, mw1_bf, 65536);
  cvt_kernel<<<256, 256, 0, stream>>>(mw2, mw2_bf, 65536);
  bkv_kernel<<<2, 256, 0, stream>>>(bk, bv, bkv);
  bias_kernel<<<1024, 256, 0, stream>>>(s_pos, x_pos, pw1, pb1, bn_g, bn_b,
                                        bn_m, bn_v, pw2, pb2, biasb);

  gemm_q<<<1024, 256, 0, stream>>>(s, Wq_bf, bq, Qa);
  gemm_tn<EPI_NONE, float, float, BF><<<2048, 256, 0, stream>>>(
      x, Wkv_bf, bkv, nullptr, KVw, 65536, 512, 256);
  attn_kernel<<<8192, 256, 0, stream>>>(Qa, KVw, biasb, ObBF);
  gemm_tn<EPI_RES, BF, float, BF><<<1024, 256, 0, stream>>>(
      ObBF, Wo_bf, bo, s, S1, 65536, 256, 256);
  ln_kernel<<<16384, 256, 0, stream>>>(S1, ln_g, ln_b, Nw);
  for (int h = 0; h < 2; ++h) {
    const size_t ro = (size_t)h * 32768;
    gemm_tn<EPI_GELU, BF, float, BF><<<2048, 256, 0, stream>>>(
        Nw + ro * 256, mw1_bf, mb1, nullptr, H2, 32768, 1024, 256);
    gemm_tn<EPI_RES, BF, BF, float><<<512, 256, 0, stream>>>(
        H2, mw2_bf, mb2, S1 + ro * 256, Of + ro * 256, 32768, 256, 1024);
  }
}

// Round 5
// 401.243 us; speedup vs baseline: 1.2169x; 1.0464x over previous
//
#include <hip/hip_runtime.h>
#include <hip/hip_bf16.h>
#include <math.h>

typedef __hip_bfloat16 BF;
typedef __bf16 bf16x8 __attribute__((ext_vector_type(8)));
typedef float f32x4 __attribute__((ext_vector_type(4)));

struct alignas(8) BF4 { BF v[4]; };
struct alignas(16) BF8 { BF v[8]; };

static __device__ __forceinline__ float b2f(BF x) { return __bfloat162float(x); }
static __device__ __forceinline__ BF f2b(float x) { return __float2bfloat16(x); }

// async global->LDS, 16B per lane; LDS dest = wave-uniform base (+lane*16 implicit)
static __device__ __forceinline__ void gld_lds16(const void* g, void* l) {
  __builtin_amdgcn_global_load_lds(
      (const __attribute__((address_space(1))) unsigned int*)g,
      (__attribute__((address_space(3))) unsigned int*)l, 16, 0, 0);
}

// ---------------------------------------------------------------------------
// f32 -> bf16 convert, 4 elements/thread, grid-stride
// ---------------------------------------------------------------------------
__global__ void __launch_bounds__(256) cvt_kernel(
    const float* __restrict__ in, BF* __restrict__ out, int n4) {
  for (int i = blockIdx.x * 256 + threadIdx.x; i < n4; i += gridDim.x * 256) {
    float4 v = ((const float4*)in)[i];
    BF4 o;
    o.v[0] = f2b(v.x); o.v[1] = f2b(v.y); o.v[2] = f2b(v.z); o.v[3] = f2b(v.w);
    ((BF4*)out)[i] = o;
  }
}

// concat bk||bv -> bkv (f32), 2 blocks x 256
__global__ void __launch_bounds__(256) bkv_kernel(
    const float* __restrict__ bk, const float* __restrict__ bv,
    float* __restrict__ bkv) {
  int i = blockIdx.x * 256 + threadIdx.x;
  bkv[i] = (i < 256) ? bk[i] : bv[i - 256];
}

// ---------------------------------------------------------------------------
// rel-bias kernel: one thread per (window w, l=qi*4+kj). out[w*128+nh*16+l], f32
// ---------------------------------------------------------------------------
__global__ void __launch_bounds__(256) bias_kernel(
    const float* __restrict__ s_pos, const float* __restrict__ x_pos,
    const float* __restrict__ pw1, const float* __restrict__ pb1,
    const float* __restrict__ bn_g, const float* __restrict__ bn_b,
    const float* __restrict__ bn_m, const float* __restrict__ bn_v,
    const float* __restrict__ pw2, const float* __restrict__ pb2,
    float* __restrict__ out) {
  int gid = blockIdx.x * 256 + threadIdx.x;   // [0, 16384*16)
  int w = gid >> 4, l = gid & 15;
  int b = w >> 12, wi = w & 4095;
  int i = l >> 2, j = l & 3;
  int e0 = i, e1 = 4 + i;
  float sp0 = s_pos[(((size_t)b * 2 + (e0 & 1)) * 4096 + wi) * 4 + (e0 >> 1)];
  float sp1 = s_pos[(((size_t)b * 2 + (e1 & 1)) * 4096 + wi) * 4 + (e1 >> 1)];
  float xp0 = x_pos[((size_t)b * 16384 + j * 4096 + wi) * 2 + 0];
  float xp1 = x_pos[((size_t)b * 16384 + j * 4096 + wi) * 2 + 1];
  float r0 = sp0 - xp0, r1 = sp1 - xp1;
  float acc[8];
#pragma unroll
  for (int p = 0; p < 8; ++p) acc[p] = pb2[p];
#pragma unroll
  for (int o = 0; o < 16; ++o) {
    float t = pw1[o * 2 + 0] * r0 + pw1[o * 2 + 1] * r1 + pb1[o];
    float sc = bn_g[o] / sqrtf(bn_v[o] + 1e-5f);
    t = (t - bn_m[o]) * sc + bn_b[o];
    t = fmaxf(t, 0.0f);
#pragma unroll
    for (int p = 0; p < 8; ++p) acc[p] += pw2[p * 16 + o] * t;
  }
#pragma unroll
  for (int p = 0; p < 8; ++p) out[(size_t)w * 128 + p * 16 + l] = acc[p];
}

// ---------------------------------------------------------------------------
// TN bf16 MFMA GEMM, single-buffer LDS (32KB -> 5 blocks/CU), m97 2-barrier
// structure + A-register prefetch (f32 A path). C = epi(A @ Bw^T + bias).
// 128x128 tile, BK=64, 4 waves 2x2, 16x16x32 MFMA, bijective XCD swizzle.
// ---------------------------------------------------------------------------
enum { EPI_NONE = 0, EPI_RES = 1, EPI_GELU = 2 };

template <int EPI, typename AT, typename RT, typename CT>
__global__ void __launch_bounds__(256, 2) gemm_tn(
    const AT* __restrict__ A, const BF* __restrict__ Bw,
    const float* __restrict__ bias, const RT* __restrict__ Res,
    CT* __restrict__ C, int M, int N, int K) {
  constexpr bool F32A = __is_same(AT, float);
  alignas(16) __shared__ BF As[8][128][8];
  alignas(16) __shared__ BF Bs[8][128][8];
  const int ntiles = N >> 7;
  const int cpx = gridDim.x >> 3;
  const int bid = blockIdx.x;
  const int swz = (bid & 7) * cpx + (bid >> 3);   // XCD-chunked, bijective
  const int mt = swz / ntiles, nt = swz % ntiles;
  const int row0 = mt << 7, col0 = nt << 7;
  const int t = threadIdx.x;
  const int wave = t >> 6, lane = t & 63;
  const int wr = wave >> 1, wc = wave & 1;
  const int sm = t & 127;      // staging row within tile
  const int skc = t >> 7;      // staging k-chunk parity
  f32x4 acc[4][4] = {};
  const int NT = K >> 6;
  float4 ar[4][2];

  auto stageB = [&](int kt) {
#pragma unroll
    for (int i = 0; i < 4; ++i) {
      const int kc = i * 2 + skc;
      gld_lds16(Bw + (size_t)(col0 + sm) * K + kt * 64 + kc * 8,
                &Bs[0][0][0] + (size_t)(i * 256 + wave * 64) * 8);
    }
  };
  auto loadA = [&](int kt) {
    if constexpr (F32A) {
#pragma unroll
      for (int i = 0; i < 4; ++i) {
        const int kc = i * 2 + skc;
        const float* src = A + (size_t)(row0 + sm) * K + kt * 64 + kc * 8;
        ar[i][0] = ((const float4*)src)[0];
        ar[i][1] = ((const float4*)src)[1];
      }
    }
  };
  auto writeA = [&]() {
    if constexpr (F32A) {
#pragma unroll
      for (int i = 0; i < 4; ++i) {
        const int kc = i * 2 + skc;
        BF tmp[8];
        tmp[0] = f2b(ar[i][0].x); tmp[1] = f2b(ar[i][0].y);
        tmp[2] = f2b(ar[i][0].z); tmp[3] = f2b(ar[i][0].w);
        tmp[4] = f2b(ar[i][1].x); tmp[5] = f2b(ar[i][1].y);
        tmp[6] = f2b(ar[i][1].z); tmp[7] = f2b(ar[i][1].w);
        *(bf16x8*)(&As[kc][sm][0]) = *(bf16x8*)tmp;
      }
    }
  };
  auto stageA_bf = [&](int kt) {
    if constexpr (!F32A) {
#pragma unroll
      for (int i = 0; i < 4; ++i) {
        const int kc = i * 2 + skc;
        gld_lds16((const BF*)A + (size_t)(row0 + sm) * K + kt * 64 + kc * 8,
                  &As[0][0][0] + (size_t)(i * 256 + wave * 64) * 8);
      }
    }
  };
  auto compute = [&]() {
#pragma unroll
    for (int kk = 0; kk < 2; ++kk) {
      const int chunk = kk * 4 + (lane >> 4);
      const int rl = lane & 15;
      bf16x8 af[4], bfr[4];
#pragma unroll
      for (int mi = 0; mi < 4; ++mi)
        af[mi] = *(const bf16x8*)(&As[chunk][wr * 64 + mi * 16 + rl][0]);
#pragma unroll
      for (int ni = 0; ni < 4; ++ni)
        bfr[ni] = *(const bf16x8*)(&Bs[chunk][wc * 64 + ni * 16 + rl][0]);
#pragma unroll
      for (int mi = 0; mi < 4; ++mi)
#pragma unroll
        for (int ni = 0; ni < 4; ++ni)
          acc[mi][ni] = __builtin_amdgcn_mfma_f32_16x16x32_bf16(
              af[mi], bfr[ni], acc[mi][ni], 0, 0, 0);
    }
  };

  loadA(0);
  for (int kt = 0; kt < NT; ++kt) {
    writeA();                       // f32 path: regs(kt) -> LDS
    stageA_bf(kt);                  // bf16 path: global -> LDS direct
    stageB(kt);
    if (kt + 1 < NT) loadA(kt + 1); // prefetch next A to regs (drains w/ stage)
    __syncthreads();                // stage visible
    compute();
    __syncthreads();                // compute done before LDS overwrite
  }

  // epilogue: D layout col = lane&15, row = (lane>>4)*4 + r (m89-verified)
  const int rl = lane & 15, rg = lane >> 4;
#pragma unroll
  for (int mi = 0; mi < 4; ++mi) {
#pragma unroll
    for (int ni = 0; ni < 4; ++ni) {
      const int col = col0 + wc * 64 + ni * 16 + rl;
      const float bcol = bias[col];
#pragma unroll
      for (int r = 0; r < 4; ++r) {
        const int row = row0 + wr * 64 + mi * 16 + rg * 4 + r;
        float v = acc[mi][ni][r] + bcol;
        if constexpr (EPI == EPI_GELU)
          v = 0.5f * v * (1.0f + erff(v * 0.70710678118654752f));
        if constexpr (EPI == EPI_RES) {
          if constexpr (__is_same(RT, float))
            v += Res[(size_t)row * N + col];
          else
            v += b2f(Res[(size_t)row * N + col]);
        }
        if constexpr (__is_same(CT, float))
          C[(size_t)row * N + col] = v;
        else
          C[(size_t)row * N + col] = f2b(v);
      }
    }
  }
}

// ---------------------------------------------------------------------------
// Q-projection GEMM writing attention layout directly (pre-scaled):
//   Qa[b][wi][nh][qi][hd] = (s @ Wq^T + bq)[b, l, c] * SCALE
//   l = nh*2048 + hd*64 + qi*16 + hi, wi = hi*256 + c.
// Single-buffer LDS, same structure as gemm_tn.
// ---------------------------------------------------------------------------
__global__ void __launch_bounds__(256, 2) gemm_q(
    const float* __restrict__ A, const BF* __restrict__ Bw,
    const float* __restrict__ bias, BF* __restrict__ Qa) {
  constexpr int K = 256;
  alignas(16) __shared__ BF As[8][128][8];
  alignas(16) __shared__ BF Bs[8][128][8];
  const int cpx = gridDim.x >> 3;
  const int bid = blockIdx.x;
  const int swz = (bid & 7) * cpx + (bid >> 3);
  const int mt = swz >> 1, nt = swz & 1;
  const int hp = mt & 3, qi = (mt >> 2) & 3, nh = (mt >> 4) & 7, bb = mt >> 7;
  const int col0 = nt << 7;
  const int t = threadIdx.x;
  const int wave = t >> 6, lane = t & 63;
  const int wr = wave >> 1, wc = wave & 1;
  const int sm = t & 127;
  const int skc = t >> 7;
  const size_t grow = (size_t)bb * 16384 + nh * 2048 + (size_t)(sm & 31) * 64 +
                      qi * 16 + hp * 4 + (sm >> 5);
  f32x4 acc[4][4] = {};
  float4 ar[4][2];

  auto stageB = [&](int kt) {
#pragma unroll
    for (int i = 0; i < 4; ++i) {
      const int kc = i * 2 + skc;
      gld_lds16(Bw + (size_t)(col0 + sm) * K + kt * 64 + kc * 8,
                &Bs[0][0][0] + (size_t)(i * 256 + wave * 64) * 8);
    }
  };
  auto loadA = [&](int kt) {
#pragma unroll
    for (int i = 0; i < 4; ++i) {
      const int kc = i * 2 + skc;
      const float* src = A + grow * K + kt * 64 + kc * 8;
      ar[i][0] = ((const float4*)src)[0];
      ar[i][1] = ((const float4*)src)[1];
    }
  };
  auto writeA = [&]() {
#pragma unroll
    for (int i = 0; i < 4; ++i) {
      const int kc = i * 2 + skc;
      BF tmp[8];
      tmp[0] = f2b(ar[i][0].x); tmp[1] = f2b(ar[i][0].y);
      tmp[2] = f2b(ar[i][0].z); tmp[3] = f2b(ar[i][0].w);
      tmp[4] = f2b(ar[i][1].x); tmp[5] = f2b(ar[i][1].y);
      tmp[6] = f2b(ar[i][1].z); tmp[7] = f2b(ar[i][1].w);
      *(bf16x8*)(&As[kc][sm][0]) = *(bf16x8*)tmp;
    }
  };
  auto compute = [&]() {
#pragma unroll
    for (int kk = 0; kk < 2; ++kk) {
      const int chunk = kk * 4 + (lane >> 4);
      const int rl = lane & 15;
      bf16x8 af[4], bfr[4];
#pragma unroll
      for (int mi = 0; mi < 4; ++mi)
        af[mi] = *(const bf16x8*)(&As[chunk][wr * 64 + mi * 16 + rl][0]);
#pragma unroll
      for (int ni = 0; ni < 4; ++ni)
        bfr[ni] = *(const bf16x8*)(&Bs[chunk][wc * 64 + ni * 16 + rl][0]);
#pragma unroll
      for (int mi = 0; mi < 4; ++mi)
#pragma unroll
        for (int ni = 0; ni < 4; ++ni)
          acc[mi][ni] = __builtin_amdgcn_mfma_f32_16x16x32_bf16(
              af[mi], bfr[ni], acc[mi][ni], 0, 0, 0);
    }
  };

  loadA(0);
  for (int kt = 0; kt < 4; ++kt) {
    writeA();
    stageB(kt);
    if (kt + 1 < 4) loadA(kt + 1);
    __syncthreads();
    compute();
    __syncthreads();
  }

  const int rl = lane & 15, rg = lane >> 4;
  const float SCALE = 0.17677669529663689f;  // 32^-0.5
#pragma unroll
  for (int mi = 0; mi < 4; ++mi) {
#pragma unroll
    for (int ni = 0; ni < 4; ++ni) {
      const int col = col0 + wc * 64 + ni * 16 + rl;
      const float bcol = bias[col];
      const int i0 = wr * 64 + mi * 16 + rg * 4;
      const int hd = i0 & 31, hil = i0 >> 5;
      const int wi = (hp * 4 + hil) * 256 + col;
      BF4 pk;
#pragma unroll
      for (int r = 0; r < 4; ++r)
        pk.v[r] = f2b((acc[mi][ni][r] + bcol) * SCALE);
      *(BF4*)(Qa + ((((size_t)bb * 4096 + wi) * 8 + nh) * 128 + qi * 32 + hd)) = pk;
    }
  }
}

// ---------------------------------------------------------------------------
// Windowed attention v3: no LDS, no QK shuffles. 16-lane group per (w,nh),
// lane = qi*4+kj. q from Qa (hd-contig, pre-scaled), k/v from KV512
// (row l_x = kj*4096+wi; cols [0:256)=K, [256:512)=V; hd-contig 64B runs).
// ---------------------------------------------------------------------------
__global__ void __launch_bounds__(256) attn_kernel(
    const BF* __restrict__ Qa, const BF* __restrict__ KV,
    const float* __restrict__ biasb, BF* __restrict__ O) {
  const int t = threadIdx.x;
  const int g = t >> 4, l16 = t & 15;
  const int qi = l16 >> 2, kj = l16 & 3;
  const int w = (blockIdx.x << 1) | (g >> 3);
  const int nh = g & 7;
  const int b = w >> 12, wi = w & 4095;

  const uint4* qp = (const uint4*)(Qa + ((((size_t)b * 4096 + wi) * 8 + nh) * 128 + qi * 32));
  uint4 qv[4] = {qp[0], qp[1], qp[2], qp[3]};
  const uint4* kp = (const uint4*)(KV + ((size_t)b * 16384 + kj * 4096 + wi) * 512 + nh * 32);
  uint4 kv[4] = {kp[0], kp[1], kp[2], kp[3]};
  const float bias_l = biasb[(size_t)w * 128 + nh * 16 + l16];
  const BF* vbase = KV + (size_t)b * 16384 * 512 + 256 + nh * 32 + kj * 8;
  uint4 vv[4];
#pragma unroll
  for (int d = 0; d < 4; ++d)
    vv[d] = *(const uint4*)(vbase + ((size_t)((kj ^ d) * 4096 + wi)) * 512);

  float accs[4] = {0.f, 0.f, 0.f, 0.f};
#pragma unroll
  for (int j = 0; j < 4; ++j) {
#pragma unroll
    for (int e = 0; e < 4; ++e) {
      unsigned qe = ((const unsigned*)&qv[j])[e];
      unsigned ke = ((const unsigned*)&kv[j])[e];
      float ql = __uint_as_float(qe << 16);
      float qh = __uint_as_float(qe & 0xffff0000u);
      float kl = __uint_as_float(ke << 16);
      float kh = __uint_as_float(ke & 0xffff0000u);
      accs[e] = fmaf(ql, kl, accs[e]);
      accs[e] = fmaf(qh, kh, accs[e]);
    }
  }
  const float score = accs[0] + accs[1] + accs[2] + accs[3] + bias_l;

  float mx = fmaxf(score, __shfl_xor(score, 1));
  mx = fmaxf(mx, __shfl_xor(mx, 2));
  float e = __expf(score - mx);
  float sm = e + __shfl_xor(e, 1);
  sm += __shfl_xor(sm, 2);
  float p = e / sm;
  float pd[4];
  pd[0] = p;
  pd[1] = __shfl_xor(p, 1);
  pd[2] = __shfl_xor(p, 2);
  pd[3] = __shfl_xor(pd[1], 2);

  float o8[8] = {0.f, 0.f, 0.f, 0.f, 0.f, 0.f, 0.f, 0.f};
#pragma unroll
  for (int d = 0; d < 4; ++d) {
#pragma unroll
    for (int e2 = 0; e2 < 4; ++e2) {
      unsigned ve = ((const unsigned*)&vv[d])[e2];
      o8[e2 * 2 + 0] = fmaf(pd[d], __uint_as_float(ve << 16), o8[e2 * 2 + 0]);
      o8[e2 * 2 + 1] = fmaf(pd[d], __uint_as_float(ve & 0xffff0000u), o8[e2 * 2 + 1]);
    }
  }
  BF8 ob;
#pragma unroll
  for (int h = 0; h < 8; ++h) ob.v[h] = f2b(o8[h]);
  *(BF8*)(O + ((size_t)b * 16384 + qi * 4096 + wi) * 256 + nh * 32 + kj * 8) = ob;
}

// ---------------------------------------------------------------------------
// LayerNorm over C=256: one 64-lane wave per row, 4 bf16 per lane.
// ---------------------------------------------------------------------------
__global__ void __launch_bounds__(256) ln_kernel(
    const BF* __restrict__ S1, const float* __restrict__ g,
    const float* __restrict__ be, BF* __restrict__ Nout) {
  const int wave = threadIdx.x >> 6, lane = threadIdx.x & 63;
  const size_t row = (size_t)blockIdx.x * 4 + wave;
  BF4 d = *(const BF4*)(S1 + row * 256 + lane * 4);
  float x[4] = {b2f(d.v[0]), b2f(d.v[1]), b2f(d.v[2]), b2f(d.v[3])};
  float s = x[0] + x[1] + x[2] + x[3];
  float sq = x[0] * x[0] + x[1] * x[1] + x[2] * x[2] + x[3] * x[3];
#pragma unroll
  for (int m = 1; m <= 32; m <<= 1) {
    s += __shfl_xor(s, m);
    sq += __shfl_xor(sq, m);
  }
  const float mean = s * 0.00390625f;
  const float var = sq * 0.00390625f - mean * mean;
  const float rstd = 1.0f / sqrtf(var + 1e-5f);
  BF4 o;
#pragma unroll
  for (int jj = 0; jj < 4; ++jj) {
    float nv = (x[jj] - mean) * rstd * g[lane * 4 + jj] + be[lane * 4 + jj];
    o.v[jj] = f2b(nv);
  }
  *(BF4*)(Nout + row * 256 + lane * 4) = o;
}

// ---------------------------------------------------------------------------
// ws layout (bytes):
//   [0,          8388608)   rel-bias f32 (nW*128)
//   [8388608,    41943040)  Qa bf16 [b][wi][nh][qi][hd] -> LN out after attn
//   [41943040,  109051904)  KV512 bf16 (65536 x 512; K|V halves) -> H2 after
//   [109051904, 142606336)  S1 bf16
//   [142606336, ~144.2MB)   bf16 weights Wq,Wo, Wkv(stacked), mw1, mw2; bkv f32
// d_out doubles as bf16 attn-output staging (consumed by Wo-GEMM, then
// overwritten with final f32 by MLP2).
// ---------------------------------------------------------------------------
extern "C" void kernel_launch(void* const* d_in, const int* in_sizes, int n_in,
                              void* d_out, int out_size, void* d_ws, size_t ws_size,
                              hipStream_t stream) {
  const float* s     = (const float*)d_in[0];
  const float* x     = (const float*)d_in[1];
  const float* s_pos = (const float*)d_in[2];
  const float* x_pos = (const float*)d_in[3];
  const float* Wq = (const float*)d_in[4];  const float* bq = (const float*)d_in[5];
  const float* Wk = (const float*)d_in[6];  const float* bk = (const float*)d_in[7];
  const float* Wv = (const float*)d_in[8];  const float* bv = (const float*)d_in[9];
  const float* Wo = (const float*)d_in[10]; const float* bo = (const float*)d_in[11];
  const float* pw1 = (const float*)d_in[12]; const float* pb1 = (const float*)d_in[13];
  const float* bn_g = (const float*)d_in[14]; const float* bn_b = (const float*)d_in[15];
  const float* bn_m = (const float*)d_in[16]; const float* bn_v = (const float*)d_in[17];
  const float* pw2 = (const float*)d_in[18]; const float* pb2 = (const float*)d_in[19];
  const float* ln_g = (const float*)d_in[20]; const float* ln_b = (const float*)d_in[21];
  const float* mw1 = (const float*)d_in[22]; const float* mb1 = (const float*)d_in[23];
  const float* mw2 = (const float*)d_in[24]; const float* mb2 = (const float*)d_in[25];

  char* ws = (char*)d_ws;
  float* biasb = (float*)ws;
  BF* Qa   = (BF*)(ws + 8388608);
  BF* KVw  = (BF*)(ws + 41943040);
  BF* S1   = (BF*)(ws + 109051904);
  BF* Wq_bf  = (BF*)(ws + 142606336);
  BF* Wo_bf  = (BF*)(ws + 142737408);
  BF* Wkv_bf = (BF*)(ws + 142868480);
  BF* mw1_bf = (BF*)(ws + 143130624);
  BF* mw2_bf = (BF*)(ws + 143654912);
  float* bkv = (float*)(ws + 144179200);
  BF* Nw = Qa;            // LN output reuses Qa region (free after attn)
  BF* H2 = KVw;           // MLP hidden reuses KV region (free after attn)
  BF* ObBF = (BF*)d_out;  // attn output staged bf16 inside d_out
  float* Of = (float*)d_out;

  cvt_kernel<<<64, 256, 0, stream>>>(Wq, Wq_bf, 16384);
  cvt_kernel<<<64, 256, 0, stream>>>(Wo, Wo_bf, 16384);
  cvt_kernel<<<64, 256, 0, stream>>>(Wk, Wkv_bf, 16384);
  cvt_kernel<<<64, 256, 0, stream>>>(Wv, Wkv_bf + 65536, 16384);
  cvt_kernel<<<256, 256, 0, stream>>>(mw1, mw1_bf, 65536);
  cvt_kernel<<<256, 256, 0, stream>>>(mw2, mw2_bf, 65536);
  bkv_kernel<<<2, 256, 0, stream>>>(bk, bv, bkv);
  bias_kernel<<<1024, 256, 0, stream>>>(s_pos, x_pos, pw1, pb1, bn_g, bn_b,
                                        bn_m, bn_v, pw2, pb2, biasb);

  gemm_q<<<1024, 256, 0, stream>>>(s, Wq_bf, bq, Qa);
  gemm_tn<EPI_NONE, float, float, BF><<<2048, 256, 0, stream>>>(
      x, Wkv_bf, bkv, nullptr, KVw, 65536, 512, 256);
  attn_kernel<<<8192, 256, 0, stream>>>(Qa, KVw, biasb, ObBF);
  gemm_tn<EPI_RES, BF, float, BF><<<1024, 256, 0, stream>>>(
      ObBF, Wo_bf, bo, s, S1, 65536, 256, 256);
  ln_kernel<<<16384, 256, 0, stream>>>(S1, ln_g, ln_b, Nw);
  for (int h = 0; h < 2; ++h) {
    const size_t ro = (size_t)h * 32768;
    gemm_tn<EPI_GELU, BF, float, BF><<<2048, 256, 0, stream>>>(
        Nw + ro * 256, mw1_bf, mb1, nullptr, H2, 32768, 1024, 256);
    gemm_tn<EPI_RES, BF, BF, float><<<512, 256, 0, stream>>>(
        H2, mw2_bf, mb2, S1 + ro * 256, Of + ro * 256, 32768, 256, 1024);
  }
}